// Round 6
// baseline (206.956 us; speedup 1.0000x reference)
//
#include <hip/hip_runtime.h>
#include <math.h>

#define NFFT  4096
#define LROW  2048
#define GLEN  298   // len(rev(w1)*rev(w1)*rev(wl)) = 100+100+100-2
#define HLEN  199   // len(rev(w1)*rev(w1))
#define OFF   1172
#define NEG2PI_D (-6.283185307179586476925286766559)
#define NEG2PI_F (-6.28318530717958647692f)
#define RSQ2  0.70710678118654752440f

// float2 LDS padding: +1 element every 16 (=128B). Verified for in-place
// strides M=1,8,64,512: each wave's b64 access lands <=2 lanes per bank-phase.
__device__ __forceinline__ int pad2(int i) { return i + (i >> 4); }

__device__ __forceinline__ float2 cadd(float2 a, float2 b) { return make_float2(a.x + b.x, a.y + b.y); }
__device__ __forceinline__ float2 csub(float2 a, float2 b) { return make_float2(a.x - b.x, a.y - b.y); }
__device__ __forceinline__ float2 cmul(float2 a, float2 b) {
  return make_float2(a.x * b.x - a.y * b.y, a.x * b.y + a.y * b.x);
}
// multiply by -i
__device__ __forceinline__ float2 cmni(float2 a) { return make_float2(a.y, -a.x); }

// DFT4 (W4 = -i)
__device__ __forceinline__ void dft4(float2 a, float2 b, float2 c, float2 d,
                                     float2& F0, float2& F1, float2& F2, float2& F3) {
  const float2 s0 = cadd(a, c), s1 = csub(a, c);
  const float2 s2 = cadd(b, d), s3 = cmni(csub(b, d));
  F0 = cadd(s0, s2); F1 = cadd(s1, s3); F2 = csub(s0, s2); F3 = csub(s1, s3);
}

// 8-point DFT (DIT even/odd), e[t] = sum_u c[u] * W8^(u*t), W8 = (1-i)/sqrt(2)
__device__ __forceinline__ void bf8(const float2 c[8], float2 e[8]) {
  float2 E0, E1, E2, E3, O0, O1, O2, O3;
  dft4(c[0], c[2], c[4], c[6], E0, E1, E2, E3);
  dft4(c[1], c[3], c[5], c[7], O0, O1, O2, O3);
  const float2 u0 = O0;
  const float2 u1 = make_float2(RSQ2 * (O1.x + O1.y), RSQ2 * (O1.y - O1.x));   // *W8
  const float2 u2 = cmni(O2);                                                  // *W8^2
  const float2 u3 = make_float2(RSQ2 * (O3.y - O3.x), -RSQ2 * (O3.x + O3.y));  // *W8^3
  e[0] = cadd(E0, u0); e[4] = csub(E0, u0);
  e[1] = cadd(E1, u1); e[5] = csub(E1, u1);
  e[2] = cadd(E2, u2); e[6] = csub(E2, u2);
  e[3] = cadd(E3, u3); e[7] = csub(E3, u3);
}

// ---------------------------------------------------------------------------
// Kernel A: g = rev(w1)*rev(w1)*rev(wl) (298 taps); G[k] = DFT_4096(g)[k]/4096,
// stored DIGIT-REVERSED (radix-8, 4 digits): Ghat[rev8(k)] = G[k], so the
// fused pointwise stage (which sees X in digit-reversed order) reads linearly.
// ---------------------------------------------------------------------------
__global__ __launch_bounds__(256)
void prep_g_kernel(const float* __restrict__ w1r, const float* __restrict__ w1i,
                   const float* __restrict__ wlr, const float* __restrict__ wli,
                   float2* __restrict__ Ghat) {
  __shared__ float hr[HLEN], hs[HLEN], gr[GLEN], gi[GLEN];
  const int tid = threadIdx.x;
  for (int n = tid; n < HLEN; n += 256) {
    float sr = 0.f, si = 0.f;
    const int lo = n > 99 ? n - 99 : 0;
    const int hh = n < 99 ? n : 99;
    for (int i = lo; i <= hh; ++i) {
      const float ar = w1r[99 - i],       ai = w1i[99 - i];
      const float br = w1r[99 - (n - i)], bi = w1i[99 - (n - i)];
      sr += ar * br - ai * bi;
      si += ar * bi + ai * br;
    }
    hr[n] = sr; hs[n] = si;
  }
  __syncthreads();
  for (int n = tid; n < GLEN; n += 256) {
    float sr = 0.f, si = 0.f;
    const int lo = n > 99 ? n - 99 : 0;
    const int hh = n < 198 ? n : 198;
    for (int i = lo; i <= hh; ++i) {
      const float ar = hr[i],             ai = hs[i];
      const float br = wlr[99 - (n - i)], bi = wli[99 - (n - i)];
      sr += ar * br - ai * bi;
      si += ar * bi + ai * br;
    }
    gr[n] = sr; gi[n] = si;
  }
  __syncthreads();
  const int k = blockIdx.x * 256 + tid;
  double s, c;
  sincos(NEG2PI_D * (double)k / (double)NFFT, &s, &c);
  double cr = 1.0, ci = 0.0, accr = 0.0, acci = 0.0;
  for (int m = 0; m < GLEN; ++m) {
    const double a = (double)gr[m], b = (double)gi[m];
    accr += a * cr - b * ci;
    acci += a * ci + b * cr;
    const double t = cr * c - ci * s;
    ci = cr * s + ci * c;
    cr = t;
  }
  const double inv = 1.0 / (double)NFFT;
  const int p = ((k & 7) << 9) | (((k >> 3) & 7) << 6) | (((k >> 6) & 7) << 3) | (k >> 9);
  Ghat[p] = make_float2((float)(accr * inv), (float)(acci * inv));
}

// ---------------------------------------------------------------------------
// In-place radix-8 stage. Locations (Q<<(SH+3)) + k + t*2^SH, k = b&(M-1),
// Q = b>>SH. Twiddle base w = W_4096^((4096>>(SH+3))*k); powers by chain.
// PRE=false: DIF (twiddle on outputs). PRE=true: DIT (twiddle on inputs).
// ---------------------------------------------------------------------------
template <int SH, bool PRE>
__device__ __forceinline__ void stage_ip(float2* A, const float2* __restrict__ Tw, int b) {
  const int M = 1 << SH;
  const int k = b & (M - 1);
  const int Q = b >> SH;
  const int base = (Q << (SH + 3)) + k;
  float2 c[8];
  #pragma unroll
  for (int t = 0; t < 8; ++t) c[t] = A[pad2(base + (t << SH))];
  const float2 w  = Tw[(NFFT >> (SH + 3)) * k];
  const float2 w2 = cmul(w, w),  w3 = cmul(w2, w),  w4 = cmul(w2, w2);
  const float2 w5 = cmul(w2, w3), w6 = cmul(w3, w3), w7 = cmul(w3, w4);
  float2 e[8];
  if (PRE) {
    c[1] = cmul(w,  c[1]); c[2] = cmul(w2, c[2]); c[3] = cmul(w3, c[3]);
    c[4] = cmul(w4, c[4]); c[5] = cmul(w5, c[5]); c[6] = cmul(w6, c[6]);
    c[7] = cmul(w7, c[7]);
    bf8(c, e);
  } else {
    bf8(c, e);
    e[1] = cmul(w,  e[1]); e[2] = cmul(w2, e[2]); e[3] = cmul(w3, e[3]);
    e[4] = cmul(w4, e[4]); e[5] = cmul(w5, e[5]); e[6] = cmul(w6, e[6]);
    e[7] = cmul(w7, e[7]);
  }
  #pragma unroll
  for (int t = 0; t < 8; ++t) A[pad2(base + (t << SH))] = e[t];
}

// ---------------------------------------------------------------------------
// Kernel B: one row per block, 512 threads, single in-place LDS buffer (38 KB
// -> 4 blocks/CU). DIF(natural->digitrev) ... fused[DIF-s3 + X^2*Ghat + conj
// + DIT-s0] ... DIT(digitrev->natural) -> |.| windowed to global.
// ---------------------------------------------------------------------------
__global__ __launch_bounds__(512, 8)
void fft_conv_kernel(const float* __restrict__ xr, const float* __restrict__ xi,
                     const float2* __restrict__ Ghat, float* __restrict__ out) {
  __shared__ float2 A[4351];             // pad2(4095) = 4350
  __shared__ float2 Tw[512];             // W_4096^j, j in [0,512)
  const int b = threadIdx.x;
  const int row = blockIdx.x;

  {  // twiddle table
    float s, c;
    sincosf(NEG2PI_F * (float)b * (1.0f / (float)NFFT), &s, &c);
    Tw[b] = make_float2(c, s);
  }
  __syncthreads();

  // ---- DIF stage 0 (SH=9, post-twiddle Tw[b]^t): global reads, c[4..7]=0
  {
    const float* xrr = xr + (size_t)row * LROW;
    const float* xir = xi + (size_t)row * LROW;
    float2 c[8];
    #pragma unroll
    for (int t = 0; t < 4; ++t) c[t] = make_float2(xrr[b + (t << 9)], xir[b + (t << 9)]);
    #pragma unroll
    for (int t = 4; t < 8; ++t) c[t] = make_float2(0.f, 0.f);
    float2 e[8];
    bf8(c, e);
    const float2 w  = Tw[b];
    const float2 w2 = cmul(w, w),  w3 = cmul(w2, w),  w4 = cmul(w2, w2);
    const float2 w5 = cmul(w2, w3), w6 = cmul(w3, w3), w7 = cmul(w3, w4);
    A[pad2(b)]              = e[0];
    A[pad2(b + (1 << 9))]   = cmul(w,  e[1]);
    A[pad2(b + (2 << 9))]   = cmul(w2, e[2]);
    A[pad2(b + (3 << 9))]   = cmul(w3, e[3]);
    A[pad2(b + (4 << 9))]   = cmul(w4, e[4]);
    A[pad2(b + (5 << 9))]   = cmul(w5, e[5]);
    A[pad2(b + (6 << 9))]   = cmul(w6, e[6]);
    A[pad2(b + (7 << 9))]   = cmul(w7, e[7]);
  }
  __syncthreads();
  stage_ip<6, false>(A, Tw, b);  __syncthreads();   // DIF stage 1
  stage_ip<3, false>(A, Tw, b);  __syncthreads();   // DIF stage 2

  // ---- fused: DIF s3 (adjacent-8, twiddle-free) -> Z = X^2*Ghat, conj ->
  //      DIT s0 (same slots, twiddle-free). All in registers, one LDS r/w.
  {
    const int base = b << 3;
    float2 c[8];
    #pragma unroll
    for (int t = 0; t < 8; ++t) c[t] = A[pad2(base + t)];
    float2 e[8];
    bf8(c, e);
    const float4* G4 = reinterpret_cast<const float4*>(Ghat + base);
    float4 gq[4];
    #pragma unroll
    for (int q = 0; q < 4; ++q) gq[q] = G4[q];
    #pragma unroll
    for (int t = 0; t < 8; ++t) {
      const float2 x = e[t];
      const float2 x2 = make_float2(x.x * x.x - x.y * x.y, 2.f * x.x * x.y);
      const float2 g = (t & 1) ? make_float2(gq[t >> 1].z, gq[t >> 1].w)
                               : make_float2(gq[t >> 1].x, gq[t >> 1].y);
      const float2 z = cmul(x2, g);
      c[t] = make_float2(z.x, -z.y);
    }
    bf8(c, e);
    #pragma unroll
    for (int t = 0; t < 8; ++t) A[pad2(base + t)] = e[t];
  }
  __syncthreads();
  stage_ip<3, true>(A, Tw, b);   __syncthreads();   // DIT stage 1
  stage_ip<6, true>(A, Tw, b);   __syncthreads();   // DIT stage 2

  // ---- DIT stage 3 (SH=9, pre-twiddle Tw[b]^t): |e_t| -> global, windowed.
  // pos = b + 512t; window [1172,3220): t=2 (b>=148), t=3,4,5 (all), t=6 (b<148)
  {
    float2 c[8];
    #pragma unroll
    for (int t = 0; t < 8; ++t) c[t] = A[pad2(b + (t << 9))];
    const float2 w  = Tw[b];
    const float2 w2 = cmul(w, w),  w3 = cmul(w2, w),  w4 = cmul(w2, w2);
    const float2 w5 = cmul(w2, w3), w6 = cmul(w3, w3), w7 = cmul(w3, w4);
    c[1] = cmul(w,  c[1]); c[2] = cmul(w2, c[2]); c[3] = cmul(w3, c[3]);
    c[4] = cmul(w4, c[4]); c[5] = cmul(w5, c[5]); c[6] = cmul(w6, c[6]);
    c[7] = cmul(w7, c[7]);
    float2 e[8];
    bf8(c, e);
    float* orow = out + (size_t)row * LROW;
    if (b >= 148) orow[b + 1024 - OFF] = sqrtf(e[2].x * e[2].x + e[2].y * e[2].y);
    orow[b + 1536 - OFF] = sqrtf(e[3].x * e[3].x + e[3].y * e[3].y);
    orow[b + 2048 - OFF] = sqrtf(e[4].x * e[4].x + e[4].y * e[4].y);
    orow[b + 2560 - OFF] = sqrtf(e[5].x * e[5].x + e[5].y * e[5].y);
    if (b < 148)  orow[b + 3072 - OFF] = sqrtf(e[6].x * e[6].x + e[6].y * e[6].y);
  }
}

// ---------------------------------------------------------------------------
extern "C" void kernel_launch(void* const* d_in, const int* in_sizes, int n_in,
                              void* d_out, int out_size, void* d_ws, size_t ws_size,
                              hipStream_t stream) {
  const float* xr  = (const float*)d_in[0];
  const float* xi  = (const float*)d_in[1];
  const float* w1r = (const float*)d_in[2];
  const float* w1i = (const float*)d_in[3];
  const float* wlr = (const float*)d_in[4];
  const float* wli = (const float*)d_in[5];
  float* out = (float*)d_out;
  float2* Ghat = (float2*)d_ws;              // 4096 * 8 B = 32 KB scratch
  const int rows = in_sizes[0] / LROW;       // 4096

  prep_g_kernel<<<NFFT / 256, 256, 0, stream>>>(w1r, w1i, wlr, wli, Ghat);
  fft_conv_kernel<<<rows, 512, 0, stream>>>(xr, xi, Ghat, out);
}

// Round 7
// 187.763 us; speedup vs baseline: 1.1022x; 1.1022x over previous
//
#include <hip/hip_runtime.h>
#include <math.h>

#define NFFT  4096
#define LROW  2048
#define GLEN  298   // len(rev(w1)*rev(w1)*rev(wl)) = 100+100+100-2
#define HLEN  199   // len(rev(w1)*rev(w1))
#define OFF   1172
#define NEG2PI_D (-6.283185307179586476925286766559)
#define NEG2PI_F (-6.28318530717958647692f)
#define RSQ2  0.70710678118654752440f

// float2 LDS padding: +1 element every 16 (=128B). Verified for in-place
// strides M=1,8,64,512: each wave's b64 access lands <=2 lanes per bank-phase.
__device__ __forceinline__ int pad2(int i) { return i + (i >> 4); }

__device__ __forceinline__ float2 cadd(float2 a, float2 b) { return make_float2(a.x + b.x, a.y + b.y); }
__device__ __forceinline__ float2 csub(float2 a, float2 b) { return make_float2(a.x - b.x, a.y - b.y); }
__device__ __forceinline__ float2 cmul(float2 a, float2 b) {
  return make_float2(a.x * b.x - a.y * b.y, a.x * b.y + a.y * b.x);
}
// multiply by -i
__device__ __forceinline__ float2 cmni(float2 a) { return make_float2(a.y, -a.x); }

// DFT4 (W4 = -i)
__device__ __forceinline__ void dft4(float2 a, float2 b, float2 c, float2 d,
                                     float2& F0, float2& F1, float2& F2, float2& F3) {
  const float2 s0 = cadd(a, c), s1 = csub(a, c);
  const float2 s2 = cadd(b, d), s3 = cmni(csub(b, d));
  F0 = cadd(s0, s2); F1 = cadd(s1, s3); F2 = csub(s0, s2); F3 = csub(s1, s3);
}

// 8-point DFT (DIT even/odd), e[t] = sum_u c[u] * W8^(u*t), W8 = (1-i)/sqrt(2)
__device__ __forceinline__ void bf8(const float2 c[8], float2 e[8]) {
  float2 E0, E1, E2, E3, O0, O1, O2, O3;
  dft4(c[0], c[2], c[4], c[6], E0, E1, E2, E3);
  dft4(c[1], c[3], c[5], c[7], O0, O1, O2, O3);
  const float2 u0 = O0;
  const float2 u1 = make_float2(RSQ2 * (O1.x + O1.y), RSQ2 * (O1.y - O1.x));   // *W8
  const float2 u2 = cmni(O2);                                                  // *W8^2
  const float2 u3 = make_float2(RSQ2 * (O3.y - O3.x), -RSQ2 * (O3.x + O3.y));  // *W8^3
  e[0] = cadd(E0, u0); e[4] = csub(E0, u0);
  e[1] = cadd(E1, u1); e[5] = csub(E1, u1);
  e[2] = cadd(E2, u2); e[6] = csub(E2, u2);
  e[3] = cadd(E3, u3); e[7] = csub(E3, u3);
}

// ---------------------------------------------------------------------------
// Kernel A: g = rev(w1)*rev(w1)*rev(wl) (298 taps); G[k] = DFT_4096(g)[k]/4096,
// stored DIGIT-REVERSED (radix-8, 4 digits): Ghat[rev8(k)] = G[k], so the
// fused pointwise stage (which sees X in digit-reversed order) reads linearly.
// ---------------------------------------------------------------------------
__global__ __launch_bounds__(256)
void prep_g_kernel(const float* __restrict__ w1r, const float* __restrict__ w1i,
                   const float* __restrict__ wlr, const float* __restrict__ wli,
                   float2* __restrict__ Ghat) {
  __shared__ float hr[HLEN], hs[HLEN], gr[GLEN], gi[GLEN];
  const int tid = threadIdx.x;
  for (int n = tid; n < HLEN; n += 256) {
    float sr = 0.f, si = 0.f;
    const int lo = n > 99 ? n - 99 : 0;
    const int hh = n < 99 ? n : 99;
    for (int i = lo; i <= hh; ++i) {
      const float ar = w1r[99 - i],       ai = w1i[99 - i];
      const float br = w1r[99 - (n - i)], bi = w1i[99 - (n - i)];
      sr += ar * br - ai * bi;
      si += ar * bi + ai * br;
    }
    hr[n] = sr; hs[n] = si;
  }
  __syncthreads();
  for (int n = tid; n < GLEN; n += 256) {
    float sr = 0.f, si = 0.f;
    const int lo = n > 99 ? n - 99 : 0;
    const int hh = n < 198 ? n : 198;
    for (int i = lo; i <= hh; ++i) {
      const float ar = hr[i],             ai = hs[i];
      const float br = wlr[99 - (n - i)], bi = wli[99 - (n - i)];
      sr += ar * br - ai * bi;
      si += ar * bi + ai * br;
    }
    gr[n] = sr; gi[n] = si;
  }
  __syncthreads();
  const int k = blockIdx.x * 256 + tid;
  double s, c;
  sincos(NEG2PI_D * (double)k / (double)NFFT, &s, &c);
  double cr = 1.0, ci = 0.0, accr = 0.0, acci = 0.0;
  for (int m = 0; m < GLEN; ++m) {
    const double a = (double)gr[m], b = (double)gi[m];
    accr += a * cr - b * ci;
    acci += a * ci + b * cr;
    const double t = cr * c - ci * s;
    ci = cr * s + ci * c;
    cr = t;
  }
  const double inv = 1.0 / (double)NFFT;
  const int p = ((k & 7) << 9) | (((k >> 3) & 7) << 6) | (((k >> 6) & 7) << 3) | (k >> 9);
  Ghat[p] = make_float2((float)(accr * inv), (float)(acci * inv));
}

// ---------------------------------------------------------------------------
// In-place radix-8 stage. Locations (Q<<(SH+3)) + k + t*2^SH, k = b&(M-1),
// Q = b>>SH. Twiddle base w = W_4096^((4096>>(SH+3))*k); powers by chain.
// PRE=false: DIF (twiddle on outputs). PRE=true: DIT (twiddle on inputs).
// ---------------------------------------------------------------------------
template <int SH, bool PRE>
__device__ __forceinline__ void stage_ip(float2* A, const float2* __restrict__ Tw, int b) {
  const int M = 1 << SH;
  const int k = b & (M - 1);
  const int Q = b >> SH;
  const int base = (Q << (SH + 3)) + k;
  float2 c[8];
  #pragma unroll
  for (int t = 0; t < 8; ++t) c[t] = A[pad2(base + (t << SH))];
  const float2 w  = Tw[(NFFT >> (SH + 3)) * k];
  const float2 w2 = cmul(w, w),  w3 = cmul(w2, w),  w4 = cmul(w2, w2);
  const float2 w5 = cmul(w2, w3), w6 = cmul(w3, w3), w7 = cmul(w3, w4);
  float2 e[8];
  if (PRE) {
    c[1] = cmul(w,  c[1]); c[2] = cmul(w2, c[2]); c[3] = cmul(w3, c[3]);
    c[4] = cmul(w4, c[4]); c[5] = cmul(w5, c[5]); c[6] = cmul(w6, c[6]);
    c[7] = cmul(w7, c[7]);
    bf8(c, e);
  } else {
    bf8(c, e);
    e[1] = cmul(w,  e[1]); e[2] = cmul(w2, e[2]); e[3] = cmul(w3, e[3]);
    e[4] = cmul(w4, e[4]); e[5] = cmul(w5, e[5]); e[6] = cmul(w6, e[6]);
    e[7] = cmul(w7, e[7]);
  }
  #pragma unroll
  for (int t = 0; t < 8; ++t) A[pad2(base + (t << SH))] = e[t];
}

// ---------------------------------------------------------------------------
// Kernel B: one row per block, 512 threads, single in-place LDS buffer (38 KB
// -> 4 blocks/CU). DIF(natural->digitrev) ... fused[DIF-s3 + X^2*Ghat + conj
// + DIT-s0] ... DIT(digitrev->natural) -> |.| windowed to global.
// __launch_bounds__(512, 4): (512,8) forced a 32-VGPR allocation -> ~185 MB
// of scratch spill traffic per dispatch (round-6 counters). 4 waves/EU keeps
// the allocator at the kernel's natural ~52-64 VGPR; HW still schedules 8
// waves/SIMD when VGPR<=64.
// ---------------------------------------------------------------------------
__global__ __launch_bounds__(512, 4)
void fft_conv_kernel(const float* __restrict__ xr, const float* __restrict__ xi,
                     const float2* __restrict__ Ghat, float* __restrict__ out) {
  __shared__ float2 A[4351];             // pad2(4095) = 4350
  __shared__ float2 Tw[512];             // W_4096^j, j in [0,512)
  const int b = threadIdx.x;
  const int row = blockIdx.x;

  {  // twiddle table
    float s, c;
    sincosf(NEG2PI_F * (float)b * (1.0f / (float)NFFT), &s, &c);
    Tw[b] = make_float2(c, s);
  }
  __syncthreads();

  // ---- DIF stage 0 (SH=9, post-twiddle Tw[b]^t): global reads, c[4..7]=0
  {
    const float* xrr = xr + (size_t)row * LROW;
    const float* xir = xi + (size_t)row * LROW;
    float2 c[8];
    #pragma unroll
    for (int t = 0; t < 4; ++t) c[t] = make_float2(xrr[b + (t << 9)], xir[b + (t << 9)]);
    #pragma unroll
    for (int t = 4; t < 8; ++t) c[t] = make_float2(0.f, 0.f);
    float2 e[8];
    bf8(c, e);
    const float2 w  = Tw[b];
    const float2 w2 = cmul(w, w),  w3 = cmul(w2, w),  w4 = cmul(w2, w2);
    const float2 w5 = cmul(w2, w3), w6 = cmul(w3, w3), w7 = cmul(w3, w4);
    A[pad2(b)]              = e[0];
    A[pad2(b + (1 << 9))]   = cmul(w,  e[1]);
    A[pad2(b + (2 << 9))]   = cmul(w2, e[2]);
    A[pad2(b + (3 << 9))]   = cmul(w3, e[3]);
    A[pad2(b + (4 << 9))]   = cmul(w4, e[4]);
    A[pad2(b + (5 << 9))]   = cmul(w5, e[5]);
    A[pad2(b + (6 << 9))]   = cmul(w6, e[6]);
    A[pad2(b + (7 << 9))]   = cmul(w7, e[7]);
  }
  __syncthreads();
  stage_ip<6, false>(A, Tw, b);  __syncthreads();   // DIF stage 1
  stage_ip<3, false>(A, Tw, b);  __syncthreads();   // DIF stage 2

  // ---- fused: DIF s3 (adjacent-8, twiddle-free) -> Z = X^2*Ghat, conj ->
  //      DIT s0 (same slots, twiddle-free). All in registers, one LDS r/w.
  {
    const int base = b << 3;
    float2 c[8];
    #pragma unroll
    for (int t = 0; t < 8; ++t) c[t] = A[pad2(base + t)];
    float2 e[8];
    bf8(c, e);
    const float4* G4 = reinterpret_cast<const float4*>(Ghat + base);
    float4 gq[4];
    #pragma unroll
    for (int q = 0; q < 4; ++q) gq[q] = G4[q];
    #pragma unroll
    for (int t = 0; t < 8; ++t) {
      const float2 x = e[t];
      const float2 x2 = make_float2(x.x * x.x - x.y * x.y, 2.f * x.x * x.y);
      const float2 g = (t & 1) ? make_float2(gq[t >> 1].z, gq[t >> 1].w)
                               : make_float2(gq[t >> 1].x, gq[t >> 1].y);
      const float2 z = cmul(x2, g);
      c[t] = make_float2(z.x, -z.y);
    }
    bf8(c, e);
    #pragma unroll
    for (int t = 0; t < 8; ++t) A[pad2(base + t)] = e[t];
  }
  __syncthreads();
  stage_ip<3, true>(A, Tw, b);   __syncthreads();   // DIT stage 1
  stage_ip<6, true>(A, Tw, b);   __syncthreads();   // DIT stage 2

  // ---- DIT stage 3 (SH=9, pre-twiddle Tw[b]^t): |e_t| -> global, windowed.
  // pos = b + 512t; window [1172,3220): t=2 (b>=148), t=3,4,5 (all), t=6 (b<148)
  {
    float2 c[8];
    #pragma unroll
    for (int t = 0; t < 8; ++t) c[t] = A[pad2(b + (t << 9))];
    const float2 w  = Tw[b];
    const float2 w2 = cmul(w, w),  w3 = cmul(w2, w),  w4 = cmul(w2, w2);
    const float2 w5 = cmul(w2, w3), w6 = cmul(w3, w3), w7 = cmul(w3, w4);
    c[1] = cmul(w,  c[1]); c[2] = cmul(w2, c[2]); c[3] = cmul(w3, c[3]);
    c[4] = cmul(w4, c[4]); c[5] = cmul(w5, c[5]); c[6] = cmul(w6, c[6]);
    c[7] = cmul(w7, c[7]);
    float2 e[8];
    bf8(c, e);
    float* orow = out + (size_t)row * LROW;
    if (b >= 148) orow[b + 1024 - OFF] = sqrtf(e[2].x * e[2].x + e[2].y * e[2].y);
    orow[b + 1536 - OFF] = sqrtf(e[3].x * e[3].x + e[3].y * e[3].y);
    orow[b + 2048 - OFF] = sqrtf(e[4].x * e[4].x + e[4].y * e[4].y);
    orow[b + 2560 - OFF] = sqrtf(e[5].x * e[5].x + e[5].y * e[5].y);
    if (b < 148)  orow[b + 3072 - OFF] = sqrtf(e[6].x * e[6].x + e[6].y * e[6].y);
  }
}

// ---------------------------------------------------------------------------
extern "C" void kernel_launch(void* const* d_in, const int* in_sizes, int n_in,
                              void* d_out, int out_size, void* d_ws, size_t ws_size,
                              hipStream_t stream) {
  const float* xr  = (const float*)d_in[0];
  const float* xi  = (const float*)d_in[1];
  const float* w1r = (const float*)d_in[2];
  const float* w1i = (const float*)d_in[3];
  const float* wlr = (const float*)d_in[4];
  const float* wli = (const float*)d_in[5];
  float* out = (float*)d_out;
  float2* Ghat = (float2*)d_ws;              // 4096 * 8 B = 32 KB scratch
  const int rows = in_sizes[0] / LROW;       // 4096

  prep_g_kernel<<<NFFT / 256, 256, 0, stream>>>(w1r, w1i, wlr, wli, Ghat);
  fft_conv_kernel<<<rows, 512, 0, stream>>>(xr, xi, Ghat, out);
}

// Round 8
// 186.886 us; speedup vs baseline: 1.1074x; 1.0047x over previous
//
#include <hip/hip_runtime.h>
#include <math.h>

#define NFFT  4096
#define LROW  2048
#define GLEN  298   // len(rev(w1)*rev(w1)*rev(wl)) = 100+100+100-2
#define HLEN  199   // len(rev(w1)*rev(w1))
#define OFF   1172
#define NEG2PI_D (-6.283185307179586476925286766559)
#define NEG2PI_F (-6.28318530717958647692f)
#define RSQ2  0.70710678118654752440f

// float2 LDS padding: +1 element every 16 (=128B).
__device__ __forceinline__ int pad2(int i) { return i + (i >> 4); }

__device__ __forceinline__ float2 cadd(float2 a, float2 b) { return make_float2(a.x + b.x, a.y + b.y); }
__device__ __forceinline__ float2 csub(float2 a, float2 b) { return make_float2(a.x - b.x, a.y - b.y); }
__device__ __forceinline__ float2 cmul(float2 a, float2 b) {
  return make_float2(a.x * b.x - a.y * b.y, a.x * b.y + a.y * b.x);
}
// multiply by -i
__device__ __forceinline__ float2 cmni(float2 a) { return make_float2(a.y, -a.x); }

// DFT4 (W4 = -i)
__device__ __forceinline__ void dft4(float2 a, float2 b, float2 c, float2 d,
                                     float2& F0, float2& F1, float2& F2, float2& F3) {
  const float2 s0 = cadd(a, c), s1 = csub(a, c);
  const float2 s2 = cadd(b, d), s3 = cmni(csub(b, d));
  F0 = cadd(s0, s2); F1 = cadd(s1, s3); F2 = csub(s0, s2); F3 = csub(s1, s3);
}

// 8-point DFT (DIT even/odd), e[t] = sum_u c[u] * W8^(u*t), W8 = (1-i)/sqrt(2)
__device__ __forceinline__ void bf8(const float2 c[8], float2 e[8]) {
  float2 E0, E1, E2, E3, O0, O1, O2, O3;
  dft4(c[0], c[2], c[4], c[6], E0, E1, E2, E3);
  dft4(c[1], c[3], c[5], c[7], O0, O1, O2, O3);
  const float2 u0 = O0;
  const float2 u1 = make_float2(RSQ2 * (O1.x + O1.y), RSQ2 * (O1.y - O1.x));   // *W8
  const float2 u2 = cmni(O2);                                                  // *W8^2
  const float2 u3 = make_float2(RSQ2 * (O3.y - O3.x), -RSQ2 * (O3.x + O3.y));  // *W8^3
  e[0] = cadd(E0, u0); e[4] = csub(E0, u0);
  e[1] = cadd(E1, u1); e[5] = csub(E1, u1);
  e[2] = cadd(E2, u2); e[6] = csub(E2, u2);
  e[3] = cadd(E3, u3); e[7] = csub(E3, u3);
}

// ---------------------------------------------------------------------------
// Kernel A: g = rev(w1)*rev(w1)*rev(wl) (298 taps); G[k] = DFT_4096(g)[k]/4096,
// stored DIGIT-REVERSED (radix-8, 4 digits) so the fused center stage (which
// sees X in digit-reversed order) reads linearly.
// ---------------------------------------------------------------------------
__global__ __launch_bounds__(256)
void prep_g_kernel(const float* __restrict__ w1r, const float* __restrict__ w1i,
                   const float* __restrict__ wlr, const float* __restrict__ wli,
                   float2* __restrict__ Ghat) {
  __shared__ float hr[HLEN], hs[HLEN], gr[GLEN], gi[GLEN];
  const int tid = threadIdx.x;
  for (int n = tid; n < HLEN; n += 256) {
    float sr = 0.f, si = 0.f;
    const int lo = n > 99 ? n - 99 : 0;
    const int hh = n < 99 ? n : 99;
    for (int i = lo; i <= hh; ++i) {
      const float ar = w1r[99 - i],       ai = w1i[99 - i];
      const float br = w1r[99 - (n - i)], bi = w1i[99 - (n - i)];
      sr += ar * br - ai * bi;
      si += ar * bi + ai * br;
    }
    hr[n] = sr; hs[n] = si;
  }
  __syncthreads();
  for (int n = tid; n < GLEN; n += 256) {
    float sr = 0.f, si = 0.f;
    const int lo = n > 99 ? n - 99 : 0;
    const int hh = n < 198 ? n : 198;
    for (int i = lo; i <= hh; ++i) {
      const float ar = hr[i],             ai = hs[i];
      const float br = wlr[99 - (n - i)], bi = wli[99 - (n - i)];
      sr += ar * br - ai * bi;
      si += ar * bi + ai * br;
    }
    gr[n] = sr; gi[n] = si;
  }
  __syncthreads();
  const int k = blockIdx.x * 256 + tid;
  double s, c;
  sincos(NEG2PI_D * (double)k / (double)NFFT, &s, &c);
  double cr = 1.0, ci = 0.0, accr = 0.0, acci = 0.0;
  for (int m = 0; m < GLEN; ++m) {
    const double a = (double)gr[m], b = (double)gi[m];
    accr += a * cr - b * ci;
    acci += a * ci + b * cr;
    const double t = cr * c - ci * s;
    ci = cr * s + ci * c;
    cr = t;
  }
  const double inv = 1.0 / (double)NFFT;
  const int p = ((k & 7) << 9) | (((k >> 3) & 7) << 6) | (((k >> 6) & 7) << 3) | (k >> 9);
  Ghat[p] = make_float2((float)(accr * inv), (float)(acci * inv));
}

// ---------------------------------------------------------------------------
// In-place radix-8 stage on TWO rows, twiddles+addresses computed once.
// Locations (Q<<(SH+3)) + k + t*2^SH, k = b&(M-1), Q = b>>SH.
// Twiddle base w = W_4096^((4096>>(SH+3))*k), read through pad2 (bank-spread).
// PRE=false: DIF (twiddle on outputs). PRE=true: DIT (twiddle on inputs).
// ---------------------------------------------------------------------------
template <int SH, bool PRE>
__device__ __forceinline__ void stage2(float2* __restrict__ A0, float2* __restrict__ A1,
                                       const float2* __restrict__ Tw, int b) {
  const int M = 1 << SH;
  const int k = b & (M - 1);
  const int Q = b >> SH;
  const int base = (Q << (SH + 3)) + k;
  int idx[8];
  #pragma unroll
  for (int t = 0; t < 8; ++t) idx[t] = pad2(base + (t << SH));
  const float2 w  = Tw[pad2((NFFT >> (SH + 3)) * k)];
  const float2 w2 = cmul(w, w),  w3 = cmul(w2, w),  w4 = cmul(w2, w2);
  const float2 w5 = cmul(w2, w3), w6 = cmul(w3, w3), w7 = cmul(w3, w4);
  #pragma unroll
  for (int r = 0; r < 2; ++r) {
    float2* A = r ? A1 : A0;
    float2 c[8];
    #pragma unroll
    for (int t = 0; t < 8; ++t) c[t] = A[idx[t]];
    float2 e[8];
    if (PRE) {
      c[1] = cmul(w,  c[1]); c[2] = cmul(w2, c[2]); c[3] = cmul(w3, c[3]);
      c[4] = cmul(w4, c[4]); c[5] = cmul(w5, c[5]); c[6] = cmul(w6, c[6]);
      c[7] = cmul(w7, c[7]);
      bf8(c, e);
    } else {
      bf8(c, e);
      e[1] = cmul(w,  e[1]); e[2] = cmul(w2, e[2]); e[3] = cmul(w3, e[3]);
      e[4] = cmul(w4, e[4]); e[5] = cmul(w5, e[5]); e[6] = cmul(w6, e[6]);
      e[7] = cmul(w7, e[7]);
    }
    #pragma unroll
    for (int t = 0; t < 8; ++t) A[idx[t]] = e[t];
  }
}

// ---------------------------------------------------------------------------
// Kernel B: TWO rows per block, 512 threads, two in-place LDS buffers (74 KB
// -> 2 blocks/CU). DIF(natural->digitrev) ... fused[DIF-s3 + X^2*Ghat + conj
// + DIT-s0] ... DIT(digitrev->natural) -> |.| windowed to global.
// Twiddle chain (6 cmuls) + pad2 addressing computed ONCE per butterfly and
// shared across both rows (~30% of per-row VALU amortized away).
// launch_bounds(512,4): round-6 showed (512,8) forces spills; natural ~56 VGPR.
// ---------------------------------------------------------------------------
__global__ __launch_bounds__(512, 4)
void fft_conv_kernel(const float* __restrict__ xr, const float* __restrict__ xi,
                     const float2* __restrict__ Ghat, float* __restrict__ out) {
  __shared__ float2 A0[4351], A1[4351];  // pad2(4095) = 4350
  __shared__ float2 Tw[543];             // pad2(511) = 542; W_4096^j, j in [0,512)
  const int b = threadIdx.x;
  const int row0 = blockIdx.x * 2;

  {  // twiddle table (padded layout -> conflict-free strided twiddle reads)
    float s, c;
    sincosf(NEG2PI_F * (float)b * (1.0f / (float)NFFT), &s, &c);
    Tw[pad2(b)] = make_float2(c, s);
  }
  __syncthreads();

  // ---- DIF stage 0 (SH=9, post-twiddle Tw[b]^t): global reads, c[4..7]=0
  {
    const float2 w  = Tw[pad2(b)];
    const float2 w2 = cmul(w, w),  w3 = cmul(w2, w),  w4 = cmul(w2, w2);
    const float2 w5 = cmul(w2, w3), w6 = cmul(w3, w3), w7 = cmul(w3, w4);
    int idx[8];
    #pragma unroll
    for (int t = 0; t < 8; ++t) idx[t] = pad2(b + (t << 9));
    #pragma unroll
    for (int r = 0; r < 2; ++r) {
      float2* A = r ? A1 : A0;
      const float* xrr = xr + (size_t)(row0 + r) * LROW;
      const float* xir = xi + (size_t)(row0 + r) * LROW;
      float2 c[8];
      #pragma unroll
      for (int t = 0; t < 4; ++t) c[t] = make_float2(xrr[b + (t << 9)], xir[b + (t << 9)]);
      #pragma unroll
      for (int t = 4; t < 8; ++t) c[t] = make_float2(0.f, 0.f);
      float2 e[8];
      bf8(c, e);
      A[idx[0]] = e[0];
      A[idx[1]] = cmul(w,  e[1]);
      A[idx[2]] = cmul(w2, e[2]);
      A[idx[3]] = cmul(w3, e[3]);
      A[idx[4]] = cmul(w4, e[4]);
      A[idx[5]] = cmul(w5, e[5]);
      A[idx[6]] = cmul(w6, e[6]);
      A[idx[7]] = cmul(w7, e[7]);
    }
  }
  __syncthreads();
  stage2<6, false>(A0, A1, Tw, b);  __syncthreads();   // DIF stage 1
  stage2<3, false>(A0, A1, Tw, b);  __syncthreads();   // DIF stage 2

  // ---- fused: DIF s3 (adjacent-8, twiddle-free) -> Z = X^2*Ghat, conj ->
  //      DIT s0 (same slots, twiddle-free). All in registers, one LDS r/w.
  {
    const int base = b << 3;
    int idx[8];
    #pragma unroll
    for (int t = 0; t < 8; ++t) idx[t] = pad2(base + t);
    const float4* G4 = reinterpret_cast<const float4*>(Ghat + base);
    float4 gq[4];
    #pragma unroll
    for (int q = 0; q < 4; ++q) gq[q] = G4[q];
    #pragma unroll
    for (int r = 0; r < 2; ++r) {
      float2* A = r ? A1 : A0;
      float2 c[8];
      #pragma unroll
      for (int t = 0; t < 8; ++t) c[t] = A[idx[t]];
      float2 e[8];
      bf8(c, e);
      #pragma unroll
      for (int t = 0; t < 8; ++t) {
        const float2 x = e[t];
        const float2 x2 = make_float2(x.x * x.x - x.y * x.y, 2.f * x.x * x.y);
        const float2 g = (t & 1) ? make_float2(gq[t >> 1].z, gq[t >> 1].w)
                                 : make_float2(gq[t >> 1].x, gq[t >> 1].y);
        const float2 z = cmul(x2, g);
        c[t] = make_float2(z.x, -z.y);
      }
      bf8(c, e);
      #pragma unroll
      for (int t = 0; t < 8; ++t) A[idx[t]] = e[t];
    }
  }
  __syncthreads();
  stage2<3, true>(A0, A1, Tw, b);   __syncthreads();   // DIT stage 1
  stage2<6, true>(A0, A1, Tw, b);   __syncthreads();   // DIT stage 2

  // ---- DIT stage 3 (SH=9, pre-twiddle Tw[b]^t): |e_t| -> global, windowed.
  // pos = b + 512t; window [1172,3220): t=2 (b>=148), t=3,4,5 (all), t=6 (b<148)
  {
    const float2 w  = Tw[pad2(b)];
    const float2 w2 = cmul(w, w),  w3 = cmul(w2, w),  w4 = cmul(w2, w2);
    const float2 w5 = cmul(w2, w3), w6 = cmul(w3, w3), w7 = cmul(w3, w4);
    int idx[8];
    #pragma unroll
    for (int t = 0; t < 8; ++t) idx[t] = pad2(b + (t << 9));
    #pragma unroll
    for (int r = 0; r < 2; ++r) {
      float2* A = r ? A1 : A0;
      float2 c[8];
      #pragma unroll
      for (int t = 0; t < 8; ++t) c[t] = A[idx[t]];
      c[1] = cmul(w,  c[1]); c[2] = cmul(w2, c[2]); c[3] = cmul(w3, c[3]);
      c[4] = cmul(w4, c[4]); c[5] = cmul(w5, c[5]); c[6] = cmul(w6, c[6]);
      c[7] = cmul(w7, c[7]);
      float2 e[8];
      bf8(c, e);
      float* orow = out + (size_t)(row0 + r) * LROW;
      if (b >= 148) orow[b + 1024 - OFF] = sqrtf(e[2].x * e[2].x + e[2].y * e[2].y);
      orow[b + 1536 - OFF] = sqrtf(e[3].x * e[3].x + e[3].y * e[3].y);
      orow[b + 2048 - OFF] = sqrtf(e[4].x * e[4].x + e[4].y * e[4].y);
      orow[b + 2560 - OFF] = sqrtf(e[5].x * e[5].x + e[5].y * e[5].y);
      if (b < 148)  orow[b + 3072 - OFF] = sqrtf(e[6].x * e[6].x + e[6].y * e[6].y);
    }
  }
}

// ---------------------------------------------------------------------------
extern "C" void kernel_launch(void* const* d_in, const int* in_sizes, int n_in,
                              void* d_out, int out_size, void* d_ws, size_t ws_size,
                              hipStream_t stream) {
  const float* xr  = (const float*)d_in[0];
  const float* xi  = (const float*)d_in[1];
  const float* w1r = (const float*)d_in[2];
  const float* w1i = (const float*)d_in[3];
  const float* wlr = (const float*)d_in[4];
  const float* wli = (const float*)d_in[5];
  float* out = (float*)d_out;
  float2* Ghat = (float2*)d_ws;              // 4096 * 8 B = 32 KB scratch
  const int rows = in_sizes[0] / LROW;       // 4096

  prep_g_kernel<<<NFFT / 256, 256, 0, stream>>>(w1r, w1i, wlr, wli, Ghat);
  fft_conv_kernel<<<rows / 2, 512, 0, stream>>>(xr, xi, Ghat, out);
}

// Round 9
// 175.704 us; speedup vs baseline: 1.1779x; 1.0636x over previous
//
#include <hip/hip_runtime.h>
#include <math.h>

#define NFFT  4096
#define LROW  2048
#define GLEN  298   // len(rev(w1)*rev(w1)*rev(wl)) = 100+100+100-2
#define HLEN  199   // len(rev(w1)*rev(w1))
#define OFF   1172
#define NEG2PI_D (-6.283185307179586476925286766559)
#define NEG2PI_F (-6.28318530717958647692f)
#define RSQ2  0.70710678118654752440f
#define C8    0.92387953251128675613f   // cos(pi/8)
#define S8    0.38268343236508977173f   // sin(pi/8)

// float2 LDS padding: +1 element every 16 (=128B). For radix-16 strides
// {1,16,256}: every wave access lands 4 lanes/bank-pair = b64 data floor.
__device__ __forceinline__ int pad2(int i) { return i + (i >> 4); }

__device__ __forceinline__ float2 cadd(float2 a, float2 b) { return make_float2(a.x + b.x, a.y + b.y); }
__device__ __forceinline__ float2 csub(float2 a, float2 b) { return make_float2(a.x - b.x, a.y - b.y); }
__device__ __forceinline__ float2 cmul(float2 a, float2 b) {
  return make_float2(a.x * b.x - a.y * b.y, a.x * b.y + a.y * b.x);
}
// multiply by -i
__device__ __forceinline__ float2 cmni(float2 a) { return make_float2(a.y, -a.x); }
// constant W16 powers: z*W16^1, ^2, ^3, ^6, ^9  (W16 = e^{-2pi i/16})
__device__ __forceinline__ float2 tw1(float2 z){ return make_float2(C8*z.x + S8*z.y, C8*z.y - S8*z.x); }
__device__ __forceinline__ float2 tw2(float2 z){ return make_float2(RSQ2*(z.x+z.y), RSQ2*(z.y-z.x)); }
__device__ __forceinline__ float2 tw3(float2 z){ return make_float2(S8*z.x + C8*z.y, S8*z.y - C8*z.x); }
__device__ __forceinline__ float2 tw6(float2 z){ return make_float2(RSQ2*(z.y-z.x), -RSQ2*(z.x+z.y)); }
__device__ __forceinline__ float2 tw9(float2 z){ return make_float2(-(C8*z.x + S8*z.y), S8*z.x - C8*z.y); }

// DFT4 (W4 = -i): F[t] = sum_q x[q] W4^{qt}
__device__ __forceinline__ void dft4(float2 a, float2 b, float2 c, float2 d,
                                     float2& F0, float2& F1, float2& F2, float2& F3) {
  const float2 s0 = cadd(a, c), s1 = csub(a, c);
  const float2 s2 = cadd(b, d), s3 = cmni(csub(b, d));
  F0 = cadd(s0, s2); F1 = cadd(s1, s3); F2 = csub(s0, s2); F3 = csub(s1, s3);
}

// DFT16 split 16 = 4x4:  X[s+4t] = DFT4_r( W16^{rs} * DFT4_q( v[4q+r] )[s] )
__device__ __forceinline__ void dft16_tail(float2 Y0[4], float2 Y1[4], float2 Y2[4],
                                           float2 Y3[4], float2 X[16]) {
  Y1[1] = tw1(Y1[1]); Y1[2] = tw2(Y1[2]); Y1[3] = tw3(Y1[3]);
  Y2[1] = tw2(Y2[1]); Y2[2] = cmni(Y2[2]); Y2[3] = tw6(Y2[3]);
  Y3[1] = tw3(Y3[1]); Y3[2] = tw6(Y3[2]); Y3[3] = tw9(Y3[3]);
  dft4(Y0[0], Y1[0], Y2[0], Y3[0], X[0], X[4], X[8],  X[12]);
  dft4(Y0[1], Y1[1], Y2[1], Y3[1], X[1], X[5], X[9],  X[13]);
  dft4(Y0[2], Y1[2], Y2[2], Y3[2], X[2], X[6], X[10], X[14]);
  dft4(Y0[3], Y1[3], Y2[3], Y3[3], X[3], X[7], X[11], X[15]);
}
__device__ __forceinline__ void dft16(const float2 v[16], float2 X[16]) {
  float2 Y0[4], Y1[4], Y2[4], Y3[4];
  dft4(v[0], v[4], v[8],  v[12], Y0[0], Y0[1], Y0[2], Y0[3]);
  dft4(v[1], v[5], v[9],  v[13], Y1[0], Y1[1], Y1[2], Y1[3]);
  dft4(v[2], v[6], v[10], v[14], Y2[0], Y2[1], Y2[2], Y2[3]);
  dft4(v[3], v[7], v[11], v[15], Y3[0], Y3[1], Y3[2], Y3[3]);
  dft16_tail(Y0, Y1, Y2, Y3, X);
}
// half: v[8..15]=0  ->  Y_r[s] = v[r] + W4^s * v[4+r]
__device__ __forceinline__ void half4(float2 a, float2 d, float2 Y[4]) {
  const float2 nd = cmni(d);
  Y[0] = cadd(a, d); Y[1] = cadd(a, nd); Y[2] = csub(a, d); Y[3] = csub(a, nd);
}

// ---------------------------------------------------------------------------
// Kernel A: g = rev(w1)*rev(w1)*rev(wl) (298 taps); G[k] = DFT_4096(g)[k]/4096,
// stored base-16 DIGIT-REVERSED so the fused center stage reads linearly.
// ---------------------------------------------------------------------------
__global__ __launch_bounds__(256)
void prep_g_kernel(const float* __restrict__ w1r, const float* __restrict__ w1i,
                   const float* __restrict__ wlr, const float* __restrict__ wli,
                   float2* __restrict__ Ghat) {
  __shared__ float hr[HLEN], hs[HLEN], gr[GLEN], gi[GLEN];
  const int tid = threadIdx.x;
  for (int n = tid; n < HLEN; n += 256) {
    float sr = 0.f, si = 0.f;
    const int lo = n > 99 ? n - 99 : 0;
    const int hh = n < 99 ? n : 99;
    for (int i = lo; i <= hh; ++i) {
      const float ar = w1r[99 - i],       ai = w1i[99 - i];
      const float br = w1r[99 - (n - i)], bi = w1i[99 - (n - i)];
      sr += ar * br - ai * bi;
      si += ar * bi + ai * br;
    }
    hr[n] = sr; hs[n] = si;
  }
  __syncthreads();
  for (int n = tid; n < GLEN; n += 256) {
    float sr = 0.f, si = 0.f;
    const int lo = n > 99 ? n - 99 : 0;
    const int hh = n < 198 ? n : 198;
    for (int i = lo; i <= hh; ++i) {
      const float ar = hr[i],             ai = hs[i];
      const float br = wlr[99 - (n - i)], bi = wli[99 - (n - i)];
      sr += ar * br - ai * bi;
      si += ar * bi + ai * br;
    }
    gr[n] = sr; gi[n] = si;
  }
  __syncthreads();
  const int k = blockIdx.x * 256 + tid;
  double s, c;
  sincos(NEG2PI_D * (double)k / (double)NFFT, &s, &c);
  double cr = 1.0, ci = 0.0, accr = 0.0, acci = 0.0;
  for (int m = 0; m < GLEN; ++m) {
    const double a = (double)gr[m], b = (double)gi[m];
    accr += a * cr - b * ci;
    acci += a * ci + b * cr;
    const double t = cr * c - ci * s;
    ci = cr * s + ci * c;
    cr = t;
  }
  const double inv = 1.0 / (double)NFFT;
  const int p = ((k & 15) << 8) | (k & 0xF0) | (k >> 8);   // base-16 digit reverse
  Ghat[p] = make_float2((float)(accr * inv), (float)(acci * inv));
}

// ---------------------------------------------------------------------------
// In-place radix-16 middle stage (stride 16). k = b&15, base = (b>>4)*256 + k,
// elements base + t*16, twiddle w = W_4096^{16k} (table), powers by chain.
// PRE=false: DIF (post-twiddle). PRE=true: DIT (pre-twiddle).
// ---------------------------------------------------------------------------
template <bool PRE>
__device__ __forceinline__ void stageB(float2* A, const float2* __restrict__ Tw, int b) {
  const int k = b & 15;
  const int base = ((b >> 4) << 8) + k;
  int idx[16];
  #pragma unroll
  for (int t = 0; t < 16; ++t) idx[t] = pad2(base + (t << 4));
  float2 v[16];
  #pragma unroll
  for (int t = 0; t < 16; ++t) v[t] = A[idx[t]];
  const float2 w = Tw[pad2(k << 4)];
  if (PRE) {
    float2 wt = w;
    v[1] = cmul(v[1], wt);
    #pragma unroll
    for (int t = 2; t < 16; ++t) { wt = cmul(wt, w); v[t] = cmul(v[t], wt); }
  }
  float2 X[16];
  dft16(v, X);
  if (!PRE) {
    float2 wt = w;
    X[1] = cmul(X[1], wt);
    #pragma unroll
    for (int t = 2; t < 16; ++t) { wt = cmul(wt, w); X[t] = cmul(X[t], wt); }
  }
  #pragma unroll
  for (int t = 0; t < 16; ++t) A[idx[t]] = X[t];
}

// ---------------------------------------------------------------------------
// Kernel B: one row per block, 256 threads x 16 elems, radix-16, 3 stages/FFT.
// StageA-fwd fuses global load (half zero); center fuses DIF-s2 + X^2*Ghat +
// conj + DIT-s0 in registers; StageA-inv fuses windowed |.| -> global.
// 6 barriers/row (vs 12 at radix-8). LDS 36.1 KB -> 4 blocks/CU.
// ---------------------------------------------------------------------------
__global__ __launch_bounds__(256, 4)
void fft_conv_kernel(const float* __restrict__ xr, const float* __restrict__ xi,
                     const float2* __restrict__ Ghat, float* __restrict__ out) {
  __shared__ float2 A[4351];   // pad2(4095) = 4350
  __shared__ float2 Tw[271];   // pad2(255) = 270; W_4096^j, j in [0,256)
  const int b = threadIdx.x;
  const int row = blockIdx.x;

  {  // twiddle table
    float s, c;
    sincosf(NEG2PI_F * (float)b * (1.0f / (float)NFFT), &s, &c);
    Tw[pad2(b)] = make_float2(c, s);
  }
  __syncthreads();

  // ---- Stage A fwd (stride 256): global reads n = b + 256t (t<8; rest 0),
  //      half-DFT16, post-twiddle W^b chain, write slots b + 256t.
  {
    const float* xrr = xr + (size_t)row * LROW;
    const float* xir = xi + (size_t)row * LROW;
    float2 v[8];
    #pragma unroll
    for (int t = 0; t < 8; ++t)
      v[t] = make_float2(xrr[b + (t << 8)], xir[b + (t << 8)]);
    float2 Y0[4], Y1[4], Y2[4], Y3[4];
    half4(v[0], v[4], Y0);
    half4(v[1], v[5], Y1);
    half4(v[2], v[6], Y2);
    half4(v[3], v[7], Y3);
    float2 X[16];
    dft16_tail(Y0, Y1, Y2, Y3, X);
    const float2 w = Tw[pad2(b)];
    float2 wt = w;
    X[1] = cmul(X[1], wt);
    #pragma unroll
    for (int t = 2; t < 16; ++t) { wt = cmul(wt, w); X[t] = cmul(X[t], wt); }
    #pragma unroll
    for (int t = 0; t < 16; ++t) A[pad2(b + (t << 8))] = X[t];
  }
  __syncthreads();
  stageB<false>(A, Tw, b);  __syncthreads();   // DIF stage 1 (stride 16)

  // ---- fused center: DIF s2 (adjacent 16, twiddle-free) -> Z = X^2*Ghat,
  //      conj -> DIT s0 (same slots, twiddle-free). One LDS round trip.
  {
    const int base = b << 4;
    int idx[16];
    #pragma unroll
    for (int t = 0; t < 16; ++t) idx[t] = pad2(base + t);
    float2 v[16];
    #pragma unroll
    for (int t = 0; t < 16; ++t) v[t] = A[idx[t]];
    float2 X[16];
    dft16(v, X);
    const float4* G4 = reinterpret_cast<const float4*>(Ghat + base);
    float4 gq[8];
    #pragma unroll
    for (int q = 0; q < 8; ++q) gq[q] = G4[q];
    #pragma unroll
    for (int t = 0; t < 16; ++t) {
      const float2 x = X[t];
      const float2 x2 = make_float2(x.x * x.x - x.y * x.y, 2.f * x.x * x.y);
      const float2 g = (t & 1) ? make_float2(gq[t >> 1].z, gq[t >> 1].w)
                               : make_float2(gq[t >> 1].x, gq[t >> 1].y);
      const float2 z = cmul(x2, g);
      v[t] = make_float2(z.x, -z.y);
    }
    dft16(v, X);
    #pragma unroll
    for (int t = 0; t < 16; ++t) A[idx[t]] = X[t];
  }
  __syncthreads();
  stageB<true>(A, Tw, b);   __syncthreads();   // DIT stage 1 (stride 16)

  // ---- Stage A inv (stride 256, pre-twiddle W^b chain): DFT16 ->
  //      |X[j]| at n = b + 256j, window [1172,3220):
  //      j=4 (b>=148), j=5..11 (all), j=12 (b<148).
  {
    float2 v[16];
    #pragma unroll
    for (int t = 0; t < 16; ++t) v[t] = A[pad2(b + (t << 8))];
    const float2 w = Tw[pad2(b)];
    float2 wt = w;
    v[1] = cmul(v[1], wt);
    #pragma unroll
    for (int t = 2; t < 16; ++t) { wt = cmul(wt, w); v[t] = cmul(v[t], wt); }
    float2 X[16];
    dft16(v, X);
    float* orow = out + (size_t)row * LROW;
    if (b >= 148)
      orow[b + 1024 - OFF] = sqrtf(X[4].x * X[4].x + X[4].y * X[4].y);
    #pragma unroll
    for (int j = 5; j < 12; ++j)
      orow[b + (j << 8) - OFF] = sqrtf(X[j].x * X[j].x + X[j].y * X[j].y);
    if (b < 148)
      orow[b + 3072 - OFF] = sqrtf(X[12].x * X[12].x + X[12].y * X[12].y);
  }
}

// ---------------------------------------------------------------------------
extern "C" void kernel_launch(void* const* d_in, const int* in_sizes, int n_in,
                              void* d_out, int out_size, void* d_ws, size_t ws_size,
                              hipStream_t stream) {
  const float* xr  = (const float*)d_in[0];
  const float* xi  = (const float*)d_in[1];
  const float* w1r = (const float*)d_in[2];
  const float* w1i = (const float*)d_in[3];
  const float* wlr = (const float*)d_in[4];
  const float* wli = (const float*)d_in[5];
  float* out = (float*)d_out;
  float2* Ghat = (float2*)d_ws;              // 4096 * 8 B = 32 KB scratch
  const int rows = in_sizes[0] / LROW;       // 4096

  prep_g_kernel<<<NFFT / 256, 256, 0, stream>>>(w1r, w1i, wlr, wli, Ghat);
  fft_conv_kernel<<<rows, 256, 0, stream>>>(xr, xi, Ghat, out);
}